// Round 1
// baseline (206.788 us; speedup 1.0000x reference)
//
#include <hip/hip_runtime.h>
#include <hip/hip_bf16.h>

typedef __attribute__((ext_vector_type(4))) short short4v;
typedef __attribute__((ext_vector_type(8))) short short8v;
typedef __attribute__((ext_vector_type(4))) float floatx4;

#define B_ROWS 2048
#define K_DIM  1024
#define N_CON  64
#define TWO_E  256
#define E_DIM  128
#define BM     128
#define BK     64
#define NT     16                              // K_DIM / BK
#define LDSA_BYTES (BM * BK * 2)               // 16384
#define LDSB_BYTES (TWO_E * BK * 2)            // 32768
#define TILE_BYTES (LDSA_BYTES + LDSB_BYTES)   // 49152
#define NBUF 3
#define SMEM_DYN (TILE_BYTES * NBUF)           // 147456 (dynamic LDS, needs attr)
#define EMB_ELEMS 16777216ULL                  // 2048*64*128
#define WT_BYTES  33554432ULL                  // 64*256*1024*2
#define XB_BYTES  4194304ULL                   // 2048*1024*2

// fp32 -> bf16 bit pattern via proven __float2bfloat16 + memcpy punning.
static __device__ inline unsigned short bf16bits(float f) {
    __hip_bfloat16 h = __float2bfloat16(f);
    unsigned short u;
    __builtin_memcpy(&u, &h, 2);
    return u;
}

// Async 16B global->LDS DMA. LDS dest = wave-uniform base + lane*16 (m104).
static __device__ inline void dma16(const void* g, void* l) {
    __builtin_amdgcn_global_load_lds(
        (const __attribute__((address_space(1))) unsigned int*)g,
        (__attribute__((address_space(3))) unsigned int*)l,
        16, 0, 0);
}

// ---------------------------------------------------------------------------
// Pre-pass (unchanged): W[n][k][o] fp32 -> Wt[n][o][k] bf16; x fp32 -> xb bf16.
// Grid (4,16,64).
// ---------------------------------------------------------------------------
__global__ void __launch_bounds__(256) prep(const float* __restrict__ W,
                                            const float* __restrict__ x,
                                            unsigned short* __restrict__ Wt,
                                            unsigned short* __restrict__ xb) {
    __shared__ unsigned int lds2[64 * 36];   // [o][kpair], padded rows
    const int tid = threadIdx.x;
    const int ot = blockIdx.x, ktile = blockIdx.y, n = blockIdx.z;
    const float* src = W + ((size_t)n * K_DIM + (size_t)ktile * 64) * TWO_E + ot * 64;
    unsigned short* dst = Wt + ((size_t)n * TWO_E + (size_t)ot * 64) * K_DIM + ktile * 64;

    const int kp = tid >> 4;
    const int c  = (tid & 15) * 4;
#pragma unroll
    for (int it = 0; it < 2; ++it) {
        const int k0 = it * 32 + kp * 2;
        floatx4 r0 = *(const floatx4*)&src[(size_t)k0 * TWO_E + c];
        floatx4 r1 = *(const floatx4*)&src[(size_t)(k0 + 1) * TWO_E + c];
#pragma unroll
        for (int j = 0; j < 4; ++j) {
            unsigned int d = (unsigned int)bf16bits(r0[j]) |
                             ((unsigned int)bf16bits(r1[j]) << 16);
            lds2[(c + j) * 36 + it * 16 + kp] = d;
        }
    }
    __syncthreads();
#pragma unroll
    for (int it = 0; it < 2; ++it) {
        int q = it * 256 + tid;
        int o = q >> 3, kc = q & 7;
        short8v v = *(short8v*)&lds2[o * 36 + kc * 4];
        *(short8v*)&dst[(size_t)o * K_DIM + kc * 8] = v;
    }

    const int bid = blockIdx.x + blockIdx.y * 4 + blockIdx.z * 64;
    const size_t base = (size_t)bid * 512 + (size_t)tid * 2;
    unsigned int d = (unsigned int)bf16bits(x[base]) |
                     ((unsigned int)bf16bits(x[base + 1]) << 16);
    ((unsigned int*)xb)[base >> 1] = d;
}

// ---------------------------------------------------------------------------
// Staging helpers: bf16 operands via global_load_lds into XOR-swizzled LDS
// (slot granule = data granule ^ (row&7), 16B granules, 128B rows; swizzle is
// applied on the GLOBAL source, LDS dest stays linear — m173 pattern).
// Per wave per tile: stage_A = 2 dma, stage_B<0,4> = 4 dma.
// ---------------------------------------------------------------------------
static __device__ inline void stage_A(const unsigned short* xrow, int kt,
                                      char* ldsA, int wave, int lane) {
#pragma unroll
    for (int it = 0; it < 2; ++it) {
        int c = it * 8 + wave;
        int s = c * 64 + lane;
        int r = s >> 3, g = s & 7;
        dma16(xrow + (size_t)r * K_DIM + kt + ((g ^ (r & 7)) * 8), ldsA + c * 1024);
    }
}

template <int I0, int I1>
static __device__ inline void stage_B(const unsigned short* wbase, int kt,
                                      char* ldsB, int wave, int lane) {
#pragma unroll
    for (int it = I0; it < I1; ++it) {
        int c = it * 8 + wave;
        int s = c * 64 + lane;
        int r = s >> 3, g = s & 7;
        dma16(wbase + (size_t)r * K_DIM + kt + ((g ^ (r & 7)) * 8), ldsB + c * 1024);
    }
}

// ---------------------------------------------------------------------------
// Pipelined fused GEMM (T3+T4+T5+T1).
// One WG = (128-row block rb) x (concept n), 512 thr / 8 waves, 1 WG/CU.
// Depth-3 LDS pipeline (3 x 48KB), counted s_waitcnt vmcnt(6) (never 0 in the
// steady loop), raw s_barrier, 2 phases/tile with 16 MFMA clusters wrapped in
// s_setprio(1). Per-wave loads/tile = 6 (A:2 + B:4), split 3+3 across phases.
// ---------------------------------------------------------------------------
__global__ void __launch_bounds__(512, 2)
concept_pipe(const unsigned short* __restrict__ xb,   // bf16 [rb*128][1024]
             const unsigned short* __restrict__ Wt,   // bf16 [n][o][k]
             const float* __restrict__ bc,
             const float* __restrict__ wp,
             const float* __restrict__ bp,
             float* __restrict__ out) {
    extern __shared__ __align__(16) char smem[];

    const int tid  = threadIdx.x;
    const int wave = tid >> 6;
    const int lane = tid & 63;
    const int lg   = lane >> 4;       // quad 0..3
    const int l15  = lane & 15;
    const int h    = wave >> 2;       // row half
    const int og   = wave & 3;        // o group

    // T1: bijective XCD swizzle. 1024 WGs, 1024 % 8 == 0. Each XCD gets 8
    // consecutive concepts -> its Wt slice (4MB) is L2-resident.
    const int lin = blockIdx.y * 16 + blockIdx.x;
    const int nid = (lin & 7) * 128 + (lin >> 3);
    const int rb  = nid & 15;
    const int n   = nid >> 4;

    int otile[4];
#pragma unroll
    for (int oi = 0; oi < 4; ++oi) otile[oi] = og * 32 + (oi & 1) * 16 + (oi & 2) * 64;

    floatx4 acc[4][4];
#pragma unroll
    for (int mi = 0; mi < 4; ++mi)
#pragma unroll
        for (int oi = 0; oi < 4; ++oi) acc[mi][oi] = (floatx4){0.f, 0.f, 0.f, 0.f};

    const unsigned short* xrow  = xb + (size_t)rb * BM * K_DIM;
    const unsigned short* wbase = Wt + (size_t)n * TWO_E * K_DIM;

    // ---- prologue: stage tiles 0 and 1 (12 dma/wave in flight) ----
    stage_A(xrow, 0, smem, wave, lane);
    stage_B<0, 4>(wbase, 0, smem + LDSA_BYTES, wave, lane);
    stage_A(xrow, BK, smem + TILE_BYTES, wave, lane);
    stage_B<0, 4>(wbase, BK, smem + TILE_BYTES + LDSA_BYTES, wave, lane);

    // validate tile 0: allow tile 1's 6 loads to stay in flight
    asm volatile("s_waitcnt vmcnt(6)" ::: "memory");
    __builtin_amdgcn_s_barrier();

    int cur = 0;
#pragma unroll 1
    for (int t = 0; t < NT; ++t) {
        char* ldsA = smem + cur * TILE_BYTES;
        char* ldsB = ldsA + LDSA_BYTES;
        int stg = cur + 2; if (stg >= NBUF) stg -= NBUF;
        char* stgA = smem + stg * TILE_BYTES;
        char* stgB = stgA + LDSA_BYTES;
        const int ktn = (t + 2) * BK;

        short8v af[4], bfr[4];

        // ================= phase 0 (ks = 0) =================
        {
            const int sw = (lg ^ (l15 & 7)) * 16;
#pragma unroll
            for (int mi = 0; mi < 4; ++mi)
                af[mi] = *(const short8v*)(ldsA + (h * 64 + mi * 16 + l15) * 128 + sw);
#pragma unroll
            for (int oi = 0; oi < 4; ++oi)
                bfr[oi] = *(const short8v*)(ldsB + (otile[oi] + l15) * 128 + sw);
        }
        if (t <= NT - 3) {                       // issue 3 dma for tile t+2
            stage_A(xrow, ktn, stgA, wave, lane);
            stage_B<0, 1>(wbase, ktn, stgB, wave, lane);
        }
        __builtin_amdgcn_s_barrier();
        asm volatile("s_waitcnt lgkmcnt(0)" ::: "memory");
        __builtin_amdgcn_sched_barrier(0);
        __builtin_amdgcn_s_setprio(1);
#pragma unroll
        for (int mi = 0; mi < 4; ++mi)
#pragma unroll
            for (int oi = 0; oi < 4; ++oi)
                acc[mi][oi] = __builtin_amdgcn_mfma_f32_16x16x32_bf16(
                    af[mi], bfr[oi], acc[mi][oi], 0, 0, 0);
        __builtin_amdgcn_s_setprio(0);
        __builtin_amdgcn_s_barrier();

        // ================= phase 1 (ks = 1) =================
        {
            const int sw = ((4 + lg) ^ (l15 & 7)) * 16;
#pragma unroll
            for (int mi = 0; mi < 4; ++mi)
                af[mi] = *(const short8v*)(ldsA + (h * 64 + mi * 16 + l15) * 128 + sw);
#pragma unroll
            for (int oi = 0; oi < 4; ++oi)
                bfr[oi] = *(const short8v*)(ldsB + (otile[oi] + l15) * 128 + sw);
        }
        if (t <= NT - 3)                         // remaining 3 dma for tile t+2
            stage_B<1, 4>(wbase, ktn, stgB, wave, lane);
        __builtin_amdgcn_s_barrier();
        asm volatile("s_waitcnt lgkmcnt(0)" ::: "memory");
        __builtin_amdgcn_sched_barrier(0);
        __builtin_amdgcn_s_setprio(1);
#pragma unroll
        for (int mi = 0; mi < 4; ++mi)
#pragma unroll
            for (int oi = 0; oi < 4; ++oi)
                acc[mi][oi] = __builtin_amdgcn_mfma_f32_16x16x32_bf16(
                    af[mi], bfr[oi], acc[mi][oi], 0, 0, 0);
        __builtin_amdgcn_s_setprio(0);

        // validate tile t+1 (counted: tile t+2's 6 loads may stay in flight)
        if (t <= NT - 3)      asm volatile("s_waitcnt vmcnt(6)" ::: "memory");
        else if (t == NT - 2) asm volatile("s_waitcnt vmcnt(0)" ::: "memory");
        if (t < NT - 1) __builtin_amdgcn_s_barrier();

        ++cur; if (cur == NBUF) cur = 0;
    }

    __syncthreads();

    // ---- epilogue (fp32, unchanged math) ----
    float biasf[4], wpf[4];
#pragma unroll
    for (int oi = 0; oi < 4; ++oi) {
        int o = otile[oi] + l15;
        biasf[oi] = bc[n * TWO_E + o];
        wpf[oi]  = wp[o];
    }
#pragma unroll
    for (int mi = 0; mi < 4; ++mi)
#pragma unroll
        for (int oi = 0; oi < 4; ++oi)
#pragma unroll
            for (int j = 0; j < 4; ++j) {
                float v = acc[mi][oi][j] + biasf[oi];
                acc[mi][oi][j] = v >= 0.f ? v : 0.01f * v;   // LeakyReLU
            }

    float* partial = (float*)smem;            // [128][4]
    float* pv      = (float*)(smem + 2048);   // [128]

#pragma unroll
    for (int mi = 0; mi < 4; ++mi)
#pragma unroll
        for (int j = 0; j < 4; ++j) {
            float ps = 0.f;
#pragma unroll
            for (int oi = 0; oi < 4; ++oi) ps += acc[mi][oi][j] * wpf[oi];
            ps += __shfl_xor(ps, 1);
            ps += __shfl_xor(ps, 2);
            ps += __shfl_xor(ps, 4);
            ps += __shfl_xor(ps, 8);
            if (l15 == 0) partial[(h * 64 + mi * 16 + lg * 4 + j) * 4 + og] = ps;
        }
    __syncthreads();

    if (tid < 128) {
        float s = partial[tid * 4] + partial[tid * 4 + 1] + partial[tid * 4 + 2] +
                  partial[tid * 4 + 3] + bp[0];
        float p = 1.f / (1.f + __expf(-s));
        pv[tid] = p;
        size_t bi = (size_t)rb * BM + tid;
        out[EMB_ELEMS + bi * N_CON + n] = p;    // c_pred
    }
    __syncthreads();

#pragma unroll
    for (int mi = 0; mi < 4; ++mi)
#pragma unroll
        for (int oi = 0; oi < 2; ++oi)
#pragma unroll
            for (int j = 0; j < 4; ++j) {
                int row = h * 64 + mi * 16 + lg * 4 + j;
                int e = og * 32 + oi * 16 + l15;
                float p = pv[row];
                float v = acc[mi][oi][j] * p + acc[mi][oi + 2][j] * (1.f - p);
                size_t bi = (size_t)rb * BM + row;
                out[(bi * N_CON + n) * E_DIM + e] = v;
            }
}

// ---------------------------------------------------------------------------
// Fallback (no workspace): previous single-buffered fp32-staging kernel.
// ---------------------------------------------------------------------------
__global__ void __launch_bounds__(512, 4)
concept_fallback(const float* __restrict__ x,
                 const float* __restrict__ Wc,
                 const float* __restrict__ bc,
                 const float* __restrict__ wp,
                 const float* __restrict__ bp,
                 float* __restrict__ out) {
    __shared__ __align__(16) char smem[TILE_BYTES];
    char* ldsA = smem;
    char* ldsB = smem + LDSA_BYTES;

    const int tid  = threadIdx.x;
    const int wave = tid >> 6;
    const int lane = tid & 63;
    const int lg   = lane >> 4;
    const int l15  = lane & 15;
    const int h    = wave >> 2;
    const int og   = wave & 3;
    const int rb = blockIdx.x;
    const int n  = blockIdx.y;

    int otile[4];
#pragma unroll
    for (int oi = 0; oi < 4; ++oi) otile[oi] = og * 32 + (oi & 1) * 16 + (oi & 2) * 64;

    floatx4 acc[4][4];
#pragma unroll
    for (int mi = 0; mi < 4; ++mi)
#pragma unroll
        for (int oi = 0; oi < 4; ++oi) acc[mi][oi] = (floatx4){0.f, 0.f, 0.f, 0.f};

    const float* xg = x + (size_t)rb * BM * K_DIM;
    const float* wg = Wc + (size_t)n * K_DIM * TWO_E;

    for (int kt = 0; kt < K_DIM; kt += BK) {
#pragma unroll
        for (int it = 0; it < 2; ++it) {
            int s = it * 512 + tid;
            int r = s >> 3, g = s & 7;
            const float* p = xg + (size_t)r * K_DIM + kt + ((g ^ (r & 7)) * 8);
            floatx4 v0 = *(const floatx4*)p, v1 = *(const floatx4*)(p + 4);
            short8v b;
            b[0] = (short)bf16bits(v0[0]); b[1] = (short)bf16bits(v0[1]);
            b[2] = (short)bf16bits(v0[2]); b[3] = (short)bf16bits(v0[3]);
            b[4] = (short)bf16bits(v1[0]); b[5] = (short)bf16bits(v1[1]);
            b[6] = (short)bf16bits(v1[2]); b[7] = (short)bf16bits(v1[3]);
            *(short8v*)(ldsA + s * 16) = b;
        }
#pragma unroll
        for (int it = 0; it < 4; ++it) {
            int s = it * 512 + tid;
            int r = s >> 3, g = s & 7;
            int k0 = kt + (g ^ (r & 7)) * 8;
            short8v b;
#pragma unroll
            for (int j = 0; j < 8; ++j)
                b[j] = (short)bf16bits(wg[(size_t)(k0 + j) * TWO_E + r]);
            *(short8v*)(ldsB + s * 16) = b;
        }
        __syncthreads();

#pragma unroll
        for (int ks = 0; ks < 2; ++ks) {
            const int sw = ((ks * 4 + lg) ^ (l15 & 7)) * 16;
            short8v af[4], bfr[4];
#pragma unroll
            for (int mi = 0; mi < 4; ++mi)
                af[mi] = *(const short8v*)(ldsA + (h * 64 + mi * 16 + l15) * 128 + sw);
#pragma unroll
            for (int oi = 0; oi < 4; ++oi)
                bfr[oi] = *(const short8v*)(ldsB + (otile[oi] + l15) * 128 + sw);
#pragma unroll
            for (int mi = 0; mi < 4; ++mi)
#pragma unroll
                for (int oi = 0; oi < 4; ++oi)
                    acc[mi][oi] = __builtin_amdgcn_mfma_f32_16x16x32_bf16(
                        af[mi], bfr[oi], acc[mi][oi], 0, 0, 0);
        }
        __syncthreads();
    }

    float biasf[4], wpf[4];
#pragma unroll
    for (int oi = 0; oi < 4; ++oi) {
        int o = otile[oi] + l15;
        biasf[oi] = bc[n * TWO_E + o];
        wpf[oi]  = wp[o];
    }
#pragma unroll
    for (int mi = 0; mi < 4; ++mi)
#pragma unroll
        for (int oi = 0; oi < 4; ++oi)
#pragma unroll
            for (int j = 0; j < 4; ++j) {
                float v = acc[mi][oi][j] + biasf[oi];
                acc[mi][oi][j] = v >= 0.f ? v : 0.01f * v;
            }

    float* partial = (float*)smem;
    float* pv      = (float*)(smem + 2048);

#pragma unroll
    for (int mi = 0; mi < 4; ++mi)
#pragma unroll
        for (int j = 0; j < 4; ++j) {
            float ps = 0.f;
#pragma unroll
            for (int oi = 0; oi < 4; ++oi) ps += acc[mi][oi][j] * wpf[oi];
            ps += __shfl_xor(ps, 1);
            ps += __shfl_xor(ps, 2);
            ps += __shfl_xor(ps, 4);
            ps += __shfl_xor(ps, 8);
            if (l15 == 0) partial[(h * 64 + mi * 16 + lg * 4 + j) * 4 + og] = ps;
        }
    __syncthreads();

    if (tid < 128) {
        float s = partial[tid * 4] + partial[tid * 4 + 1] + partial[tid * 4 + 2] +
                  partial[tid * 4 + 3] + bp[0];
        float p = 1.f / (1.f + __expf(-s));
        pv[tid] = p;
        size_t bi = (size_t)rb * BM + tid;
        out[EMB_ELEMS + bi * N_CON + n] = p;
    }
    __syncthreads();

#pragma unroll
    for (int mi = 0; mi < 4; ++mi)
#pragma unroll
        for (int oi = 0; oi < 2; ++oi)
#pragma unroll
            for (int j = 0; j < 4; ++j) {
                int row = h * 64 + mi * 16 + lg * 4 + j;
                int e = og * 32 + oi * 16 + l15;
                float p = pv[row];
                float v = acc[mi][oi][j] * p + acc[mi][oi + 2][j] * (1.f - p);
                size_t bi = (size_t)rb * BM + row;
                out[(bi * N_CON + n) * E_DIM + e] = v;
            }
}

extern "C" void kernel_launch(void* const* d_in, const int* in_sizes, int n_in,
                              void* d_out, int out_size, void* d_ws, size_t ws_size,
                              hipStream_t stream) {
    const float* x  = (const float*)d_in[0];
    const float* Wc = (const float*)d_in[1];
    const float* bc = (const float*)d_in[2];
    const float* wp = (const float*)d_in[3];
    const float* bp = (const float*)d_in[4];
    float* out = (float*)d_out;

    if (ws_size >= WT_BYTES + XB_BYTES) {
        static bool s_attr_done = false;
        if (!s_attr_done) {
            hipFuncSetAttribute((const void*)concept_pipe,
                                hipFuncAttributeMaxDynamicSharedMemorySize,
                                SMEM_DYN);
            s_attr_done = true;
        }
        unsigned short* Wt = (unsigned short*)d_ws;
        unsigned short* xb = (unsigned short*)((char*)d_ws + WT_BYTES);
        prep<<<dim3(4, 16, 64), 256, 0, stream>>>(Wc, x, Wt, xb);
        concept_pipe<<<dim3(16, 64), 512, SMEM_DYN, stream>>>(
            xb, Wt, bc, wp, bp, out);
    } else {
        concept_fallback<<<dim3(16, 64), 512, 0, stream>>>(
            x, Wc, bc, wp, bp, out);
    }
}

// Round 2
// 198.115 us; speedup vs baseline: 1.0438x; 1.0438x over previous
//
#include <hip/hip_runtime.h>
#include <hip/hip_bf16.h>

typedef __attribute__((ext_vector_type(4))) short short4v;
typedef __attribute__((ext_vector_type(8))) short short8v;
typedef __attribute__((ext_vector_type(4))) float floatx4;

#define B_ROWS 2048
#define K_DIM  1024
#define N_CON  64
#define TWO_E  256
#define E_DIM  128
#define BM     256
#define BK     64
#define NT     16                              // K_DIM / BK
#define LDSA_BYTES (BM * BK * 2)               // 32768
#define LDSB_BYTES (TWO_E * BK * 2)            // 32768
#define TILE_BYTES (LDSA_BYTES + LDSB_BYTES)   // 65536
#define SMEM_DYN (TILE_BYTES * 2)              // 131072 dynamic LDS
#define EMB_ELEMS 16777216ULL                  // 2048*64*128
#define WT_BYTES  33554432ULL                  // 64*256*1024*2
#define XB_BYTES  4194304ULL                   // 2048*1024*2

// fp32 -> bf16 bit pattern via proven __float2bfloat16 + memcpy punning.
static __device__ inline unsigned short bf16bits(float f) {
    __hip_bfloat16 h = __float2bfloat16(f);
    unsigned short u;
    __builtin_memcpy(&u, &h, 2);
    return u;
}

// Async 16B global->LDS DMA. LDS dest = wave-uniform base + lane*16 (m104).
static __device__ inline void dma16(const void* g, void* l) {
    __builtin_amdgcn_global_load_lds(
        (const __attribute__((address_space(1))) unsigned int*)g,
        (__attribute__((address_space(3))) unsigned int*)l,
        16, 0, 0);
}

// ---------------------------------------------------------------------------
// Pre-pass (unchanged): W[n][k][o] fp32 -> Wt[n][o][k] bf16; x fp32 -> xb bf16.
// Grid (4,16,64).
// ---------------------------------------------------------------------------
__global__ void __launch_bounds__(256) prep(const float* __restrict__ W,
                                            const float* __restrict__ x,
                                            unsigned short* __restrict__ Wt,
                                            unsigned short* __restrict__ xb) {
    __shared__ unsigned int lds2[64 * 36];   // [o][kpair], padded rows
    const int tid = threadIdx.x;
    const int ot = blockIdx.x, ktile = blockIdx.y, n = blockIdx.z;
    const float* src = W + ((size_t)n * K_DIM + (size_t)ktile * 64) * TWO_E + ot * 64;
    unsigned short* dst = Wt + ((size_t)n * TWO_E + (size_t)ot * 64) * K_DIM + ktile * 64;

    const int kp = tid >> 4;
    const int c  = (tid & 15) * 4;
#pragma unroll
    for (int it = 0; it < 2; ++it) {
        const int k0 = it * 32 + kp * 2;
        floatx4 r0 = *(const floatx4*)&src[(size_t)k0 * TWO_E + c];
        floatx4 r1 = *(const floatx4*)&src[(size_t)(k0 + 1) * TWO_E + c];
#pragma unroll
        for (int j = 0; j < 4; ++j) {
            unsigned int d = (unsigned int)bf16bits(r0[j]) |
                             ((unsigned int)bf16bits(r1[j]) << 16);
            lds2[(c + j) * 36 + it * 16 + kp] = d;
        }
    }
    __syncthreads();
#pragma unroll
    for (int it = 0; it < 2; ++it) {
        int q = it * 256 + tid;
        int o = q >> 3, kc = q & 7;
        short8v v = *(short8v*)&lds2[o * 36 + kc * 4];
        *(short8v*)&dst[(size_t)o * K_DIM + kc * 8] = v;
    }

    const int bid = blockIdx.x + blockIdx.y * 4 + blockIdx.z * 64;
    const size_t base = (size_t)bid * 512 + (size_t)tid * 2;
    unsigned int d = (unsigned int)bf16bits(x[base]) |
                     ((unsigned int)bf16bits(x[base + 1]) << 16);
    ((unsigned int*)xb)[base >> 1] = d;
}

// ---------------------------------------------------------------------------
// Staging: one chunk = 64 granules of 16B = 8 LDS rows (1KB LDS, wave-linear
// dest; XOR swizzle applied on the GLOBAL source — m173 pattern).
// A/B tiles are 32 chunks each; chunk c = IT*8 + wave; IT selects a 64-row
// quarter: IT0 rows 0-63, IT1 64-127, IT2 128-191, IT3 192-255.
// ---------------------------------------------------------------------------
template <int IT>
static __device__ inline void stA(const unsigned short* base, int kt,
                                  char* lds, int wave, int lane) {
    int c = IT * 8 + wave;
    int s = c * 64 + lane;
    int r = s >> 3, g = s & 7;
    dma16(base + (size_t)r * K_DIM + kt + ((g ^ (r & 7)) * 8), lds + c * 1024);
}

// ---------------------------------------------------------------------------
// m201-faithful 256x256 schedule. One WG = (256-row block rb) x (concept n),
// 512 thr / 8 waves (2M x 4N), per-wave output 128x64. 2 LDS buffers (128KB).
// Per K-tile: 4 quadrant phases with register-carried fragment reuse
// (24 ds_read_b128/wave/K-tile); region-granular staging of tile t+2 into the
// CURRENT buffer as regions free (P1: A-q0,q2 + B-half0; P2: B-half1;
// P3: A-q1,q3); one counted s_waitcnt vmcnt(8) per K-tile (never 0 in steady
// state); setprio(1) around each 16-MFMA cluster.
// ---------------------------------------------------------------------------
__global__ void __launch_bounds__(512, 2)
concept_256(const unsigned short* __restrict__ xb,   // bf16 [2048][1024]
            const unsigned short* __restrict__ Wt,   // bf16 [n][o][k]
            const float* __restrict__ bc,
            const float* __restrict__ wp,
            const float* __restrict__ bp,
            float* __restrict__ out) {
    extern __shared__ __align__(16) char smem[];

    const int tid  = threadIdx.x;
    const int wave = tid >> 6;
    const int lane = tid & 63;
    const int lg   = lane >> 4;       // quad 0..3
    const int l15  = lane & 15;
    const int h    = wave >> 2;       // row half (128 rows each)
    const int og   = wave & 3;        // o group

    // T1 bijective XCD swizzle: 512 WGs, XCD k gets n in [k*8, k*8+8).
    const int lin = blockIdx.y * 8 + blockIdx.x;
    const int nid = (lin & 7) * 64 + (lin >> 3);
    const int rb  = nid & 7;          // 0..7 (256 rows each)
    const int n   = nid >> 3;         // 0..63

    int otile[4];
#pragma unroll
    for (int oi = 0; oi < 4; ++oi) otile[oi] = og * 32 + (oi & 1) * 16 + (oi & 2) * 64;

    floatx4 acc[8][4];
#pragma unroll
    for (int mi = 0; mi < 8; ++mi)
#pragma unroll
        for (int oi = 0; oi < 4; ++oi) acc[mi][oi] = (floatx4){0.f, 0.f, 0.f, 0.f};

    const unsigned short* xrow  = xb + (size_t)rb * BM * K_DIM;
    const unsigned short* wbase = Wt + (size_t)n * TWO_E * K_DIM;

    char* bufA0 = smem;
    char* bufB0 = smem + LDSA_BYTES;
    char* bufA1 = smem + TILE_BYTES;
    char* bufB1 = bufA1 + LDSA_BYTES;

    // ---- prologue: fully stage tiles 0 (buf0) and 1 (buf1): 8 dma each ----
    stA<0>(xrow, 0, bufA0, wave, lane);  stA<1>(xrow, 0, bufA0, wave, lane);
    stA<2>(xrow, 0, bufA0, wave, lane);  stA<3>(xrow, 0, bufA0, wave, lane);
    stA<0>(wbase, 0, bufB0, wave, lane); stA<1>(wbase, 0, bufB0, wave, lane);
    stA<2>(wbase, 0, bufB0, wave, lane); stA<3>(wbase, 0, bufB0, wave, lane);
    stA<0>(xrow, BK, bufA1, wave, lane);  stA<1>(xrow, BK, bufA1, wave, lane);
    stA<2>(xrow, BK, bufA1, wave, lane);  stA<3>(xrow, BK, bufA1, wave, lane);
    stA<0>(wbase, BK, bufB1, wave, lane); stA<1>(wbase, BK, bufB1, wave, lane);
    stA<2>(wbase, BK, bufB1, wave, lane); stA<3>(wbase, BK, bufB1, wave, lane);

    asm volatile("s_waitcnt vmcnt(8)" ::: "memory");   // tile 0 landed
    __builtin_amdgcn_s_barrier();

    const int arow0 = h * 128;
    short8v af[4][2], bf[2][2], bf2[2][2];

#pragma unroll 1
    for (int t = 0; t < NT; ++t) {
        char* ldsA = smem + (t & 1) * TILE_BYTES;      // tile t (and t+2) home
        char* ldsB = ldsA + LDSA_BYTES;
        const bool stg = (t + 2 < NT);
        const int ktn = (t + 2) * BK;

        // ======== P0: Q(mihalf0, ohalf0) — 12 reads, 16 MFMA ========
#pragma unroll
        for (int ks = 0; ks < 2; ++ks) {
            const int sw = ((ks * 4 + lg) ^ (l15 & 7)) * 16;
#pragma unroll
            for (int mi = 0; mi < 4; ++mi)
                af[mi][ks] = *(const short8v*)(ldsA + (arow0 + mi * 16 + l15) * 128 + sw);
#pragma unroll
            for (int oi = 0; oi < 2; ++oi)
                bf[oi][ks] = *(const short8v*)(ldsB + (otile[oi] + l15) * 128 + sw);
        }
        asm volatile("s_waitcnt lgkmcnt(8)" ::: "memory");
        __builtin_amdgcn_s_barrier();
        asm volatile("s_waitcnt lgkmcnt(0)" ::: "memory");
        __builtin_amdgcn_sched_barrier(0);
        __builtin_amdgcn_s_setprio(1);
#pragma unroll
        for (int mi = 0; mi < 4; ++mi)
#pragma unroll
            for (int oi = 0; oi < 2; ++oi)
#pragma unroll
                for (int ks = 0; ks < 2; ++ks)
                    acc[mi][oi] = __builtin_amdgcn_mfma_f32_16x16x32_bf16(
                        af[mi][ks], bf[oi][ks], acc[mi][oi], 0, 0, 0);
        __builtin_amdgcn_s_setprio(0);
        __builtin_amdgcn_s_barrier();

        // ======== P1: Q(mihalf0, ohalf1) — 4 reads, 4 dma, 16 MFMA ========
#pragma unroll
        for (int ks = 0; ks < 2; ++ks) {
            const int sw = ((ks * 4 + lg) ^ (l15 & 7)) * 16;
#pragma unroll
            for (int oi = 0; oi < 2; ++oi)
                bf2[oi][ks] = *(const short8v*)(ldsB + (otile[2 + oi] + l15) * 128 + sw);
        }
        if (stg) {                               // regions freed after P0
            stA<0>(xrow, ktn, ldsA, wave, lane); // A rows 0-63
            stA<2>(xrow, ktn, ldsA, wave, lane); // A rows 128-191
            stA<0>(wbase, ktn, ldsB, wave, lane);// B rows 0-63
            stA<1>(wbase, ktn, ldsB, wave, lane);// B rows 64-127
        }
        __builtin_amdgcn_s_barrier();
        asm volatile("s_waitcnt lgkmcnt(0)" ::: "memory");
        __builtin_amdgcn_sched_barrier(0);
        __builtin_amdgcn_s_setprio(1);
#pragma unroll
        for (int mi = 0; mi < 4; ++mi)
#pragma unroll
            for (int oi = 0; oi < 2; ++oi)
#pragma unroll
                for (int ks = 0; ks < 2; ++ks)
                    acc[mi][2 + oi] = __builtin_amdgcn_mfma_f32_16x16x32_bf16(
                        af[mi][ks], bf2[oi][ks], acc[mi][2 + oi], 0, 0, 0);
        __builtin_amdgcn_s_setprio(0);
        __builtin_amdgcn_s_barrier();

        // ======== P2: Q(mihalf1, ohalf1) — 8 reads, 2 dma, 16 MFMA ========
#pragma unroll
        for (int ks = 0; ks < 2; ++ks) {
            const int sw = ((ks * 4 + lg) ^ (l15 & 7)) * 16;
#pragma unroll
            for (int mi = 0; mi < 4; ++mi)
                af[mi][ks] = *(const short8v*)(ldsA + (arow0 + 64 + mi * 16 + l15) * 128 + sw);
        }
        if (stg) {                               // B-half1 freed after P1
            stA<2>(wbase, ktn, ldsB, wave, lane);// B rows 128-191
            stA<3>(wbase, ktn, ldsB, wave, lane);// B rows 192-255
        }
        __builtin_amdgcn_s_barrier();
        asm volatile("s_waitcnt lgkmcnt(0)" ::: "memory");
        __builtin_amdgcn_sched_barrier(0);
        __builtin_amdgcn_s_setprio(1);
#pragma unroll
        for (int mi = 0; mi < 4; ++mi)
#pragma unroll
            for (int oi = 0; oi < 2; ++oi)
#pragma unroll
                for (int ks = 0; ks < 2; ++ks)
                    acc[4 + mi][2 + oi] = __builtin_amdgcn_mfma_f32_16x16x32_bf16(
                        af[mi][ks], bf2[oi][ks], acc[4 + mi][2 + oi], 0, 0, 0);
        __builtin_amdgcn_s_setprio(0);
        __builtin_amdgcn_s_barrier();

        // ======== P3: Q(mihalf1, ohalf0) — 0 reads, 2 dma, 16 MFMA ========
        if (stg) {                               // A q1/q3 freed after P2
            stA<1>(xrow, ktn, ldsA, wave, lane); // A rows 64-127
            stA<3>(xrow, ktn, ldsA, wave, lane); // A rows 192-255
        }
        __builtin_amdgcn_s_setprio(1);
#pragma unroll
        for (int mi = 0; mi < 4; ++mi)
#pragma unroll
            for (int oi = 0; oi < 2; ++oi)
#pragma unroll
                for (int ks = 0; ks < 2; ++ks)
                    acc[4 + mi][oi] = __builtin_amdgcn_mfma_f32_16x16x32_bf16(
                        af[mi][ks], bf[oi][ks], acc[4 + mi][oi], 0, 0, 0);
        __builtin_amdgcn_s_setprio(0);

        // counted validate of tile t+1: only tile t+2's 8 dma may be in flight
        if (stg) asm volatile("s_waitcnt vmcnt(8)" ::: "memory");
        else     asm volatile("s_waitcnt vmcnt(0)" ::: "memory");
        __builtin_amdgcn_s_barrier();
    }

    // ---- epilogue (fp32) ----
    float biasf[4], wpf[4];
#pragma unroll
    for (int oi = 0; oi < 4; ++oi) {
        int o = otile[oi] + l15;
        biasf[oi] = bc[n * TWO_E + o];
        wpf[oi]  = wp[o];
    }
#pragma unroll
    for (int mi = 0; mi < 8; ++mi)
#pragma unroll
        for (int oi = 0; oi < 4; ++oi)
#pragma unroll
            for (int j = 0; j < 4; ++j) {
                float v = acc[mi][oi][j] + biasf[oi];
                acc[mi][oi][j] = v >= 0.f ? v : 0.01f * v;   // LeakyReLU
            }

    float* partial = (float*)smem;            // [256][4]
    float* pv      = (float*)(smem + 4096);   // [256]

#pragma unroll
    for (int mi = 0; mi < 8; ++mi)
#pragma unroll
        for (int j = 0; j < 4; ++j) {
            float ps = 0.f;
#pragma unroll
            for (int oi = 0; oi < 4; ++oi) ps += acc[mi][oi][j] * wpf[oi];
            ps += __shfl_xor(ps, 1);
            ps += __shfl_xor(ps, 2);
            ps += __shfl_xor(ps, 4);
            ps += __shfl_xor(ps, 8);
            if (l15 == 0) partial[(h * 128 + mi * 16 + lg * 4 + j) * 4 + og] = ps;
        }
    __syncthreads();

    if (tid < 256) {
        float s = partial[tid * 4] + partial[tid * 4 + 1] + partial[tid * 4 + 2] +
                  partial[tid * 4 + 3] + bp[0];
        float p = 1.f / (1.f + __expf(-s));
        pv[tid] = p;
        size_t bi = (size_t)rb * BM + tid;
        out[EMB_ELEMS + bi * N_CON + n] = p;    // c_pred
    }
    __syncthreads();

#pragma unroll
    for (int mi = 0; mi < 8; ++mi)
#pragma unroll
        for (int oi = 0; oi < 2; ++oi)
#pragma unroll
            for (int j = 0; j < 4; ++j) {
                int row = h * 128 + mi * 16 + lg * 4 + j;
                int e = og * 32 + oi * 16 + l15;
                float p = pv[row];
                float v = acc[mi][oi][j] * p + acc[mi][oi + 2][j] * (1.f - p);
                size_t bi = (size_t)rb * BM + row;
                out[(bi * N_CON + n) * E_DIM + e] = v;
            }
}

// ---------------------------------------------------------------------------
// Fallback (no workspace): single-buffered fp32-staging kernel (verified).
// ---------------------------------------------------------------------------
__global__ void __launch_bounds__(512, 4)
concept_fallback(const float* __restrict__ x,
                 const float* __restrict__ Wc,
                 const float* __restrict__ bc,
                 const float* __restrict__ wp,
                 const float* __restrict__ bp,
                 float* __restrict__ out) {
    __shared__ __align__(16) char smem[49152];
    char* ldsA = smem;
    char* ldsB = smem + 16384;

    const int tid  = threadIdx.x;
    const int wave = tid >> 6;
    const int lane = tid & 63;
    const int lg   = lane >> 4;
    const int l15  = lane & 15;
    const int h    = wave >> 2;
    const int og   = wave & 3;
    const int rb = blockIdx.x;
    const int n  = blockIdx.y;

    int otile[4];
#pragma unroll
    for (int oi = 0; oi < 4; ++oi) otile[oi] = og * 32 + (oi & 1) * 16 + (oi & 2) * 64;

    floatx4 acc[4][4];
#pragma unroll
    for (int mi = 0; mi < 4; ++mi)
#pragma unroll
        for (int oi = 0; oi < 4; ++oi) acc[mi][oi] = (floatx4){0.f, 0.f, 0.f, 0.f};

    const float* xg = x + (size_t)rb * 128 * K_DIM;
    const float* wg = Wc + (size_t)n * K_DIM * TWO_E;

    for (int kt = 0; kt < K_DIM; kt += BK) {
#pragma unroll
        for (int it = 0; it < 2; ++it) {
            int s = it * 512 + tid;
            int r = s >> 3, g = s & 7;
            const float* p = xg + (size_t)r * K_DIM + kt + ((g ^ (r & 7)) * 8);
            floatx4 v0 = *(const floatx4*)p, v1 = *(const floatx4*)(p + 4);
            short8v b;
            b[0] = (short)bf16bits(v0[0]); b[1] = (short)bf16bits(v0[1]);
            b[2] = (short)bf16bits(v0[2]); b[3] = (short)bf16bits(v0[3]);
            b[4] = (short)bf16bits(v1[0]); b[5] = (short)bf16bits(v1[1]);
            b[6] = (short)bf16bits(v1[2]); b[7] = (short)bf16bits(v1[3]);
            *(short8v*)(ldsA + s * 16) = b;
        }
#pragma unroll
        for (int it = 0; it < 4; ++it) {
            int s = it * 512 + tid;
            int r = s >> 3, g = s & 7;
            int k0 = kt + (g ^ (r & 7)) * 8;
            short8v b;
#pragma unroll
            for (int j = 0; j < 8; ++j)
                b[j] = (short)bf16bits(wg[(size_t)(k0 + j) * TWO_E + r]);
            *(short8v*)(ldsB + s * 16) = b;
        }
        __syncthreads();

#pragma unroll
        for (int ks = 0; ks < 2; ++ks) {
            const int sw = ((ks * 4 + lg) ^ (l15 & 7)) * 16;
            short8v af[4], bfr[4];
#pragma unroll
            for (int mi = 0; mi < 4; ++mi)
                af[mi] = *(const short8v*)(ldsA + (h * 64 + mi * 16 + l15) * 128 + sw);
#pragma unroll
            for (int oi = 0; oi < 4; ++oi)
                bfr[oi] = *(const short8v*)(ldsB + (otile[oi] + l15) * 128 + sw);
#pragma unroll
            for (int mi = 0; mi < 4; ++mi)
#pragma unroll
                for (int oi = 0; oi < 4; ++oi)
                    acc[mi][oi] = __builtin_amdgcn_mfma_f32_16x16x32_bf16(
                        af[mi], bfr[oi], acc[mi][oi], 0, 0, 0);
        }
        __syncthreads();
    }

    float biasf[4], wpf[4];
#pragma unroll
    for (int oi = 0; oi < 4; ++oi) {
        int o = otile[oi] + l15;
        biasf[oi] = bc[n * TWO_E + o];
        wpf[oi]  = wp[o];
    }
#pragma unroll
    for (int mi = 0; mi < 4; ++mi)
#pragma unroll
        for (int oi = 0; oi < 4; ++oi)
#pragma unroll
            for (int j = 0; j < 4; ++j) {
                float v = acc[mi][oi][j] + biasf[oi];
                acc[mi][oi][j] = v >= 0.f ? v : 0.01f * v;
            }

    float* partial = (float*)smem;
    float* pv      = (float*)(smem + 2048);

#pragma unroll
    for (int mi = 0; mi < 4; ++mi)
#pragma unroll
        for (int j = 0; j < 4; ++j) {
            float ps = 0.f;
#pragma unroll
            for (int oi = 0; oi < 4; ++oi) ps += acc[mi][oi][j] * wpf[oi];
            ps += __shfl_xor(ps, 1);
            ps += __shfl_xor(ps, 2);
            ps += __shfl_xor(ps, 4);
            ps += __shfl_xor(ps, 8);
            if (l15 == 0) partial[(h * 64 + mi * 16 + lg * 4 + j) * 4 + og] = ps;
        }
    __syncthreads();

    if (tid < 128) {
        float s = partial[tid * 4] + partial[tid * 4 + 1] + partial[tid * 4 + 2] +
                  partial[tid * 4 + 3] + bp[0];
        float p = 1.f / (1.f + __expf(-s));
        pv[tid] = p;
        size_t bi = (size_t)rb * 128 + tid;
        out[EMB_ELEMS + bi * N_CON + n] = p;
    }
    __syncthreads();

#pragma unroll
    for (int mi = 0; mi < 4; ++mi)
#pragma unroll
        for (int oi = 0; oi < 2; ++oi)
#pragma unroll
            for (int j = 0; j < 4; ++j) {
                int row = h * 64 + mi * 16 + lg * 4 + j;
                int e = og * 32 + oi * 16 + l15;
                float p = pv[row];
                float v = acc[mi][oi][j] * p + acc[mi][oi + 2][j] * (1.f - p);
                size_t bi = (size_t)rb * 128 + row;
                out[(bi * N_CON + n) * E_DIM + e] = v;
            }
}

extern "C" void kernel_launch(void* const* d_in, const int* in_sizes, int n_in,
                              void* d_out, int out_size, void* d_ws, size_t ws_size,
                              hipStream_t stream) {
    const float* x  = (const float*)d_in[0];
    const float* Wc = (const float*)d_in[1];
    const float* bc = (const float*)d_in[2];
    const float* wp = (const float*)d_in[3];
    const float* bp = (const float*)d_in[4];
    float* out = (float*)d_out;

    if (ws_size >= WT_BYTES + XB_BYTES) {
        static bool s_attr_done = false;
        if (!s_attr_done) {
            hipFuncSetAttribute((const void*)concept_256,
                                hipFuncAttributeMaxDynamicSharedMemorySize,
                                SMEM_DYN);
            s_attr_done = true;
        }
        unsigned short* Wt = (unsigned short*)d_ws;
        unsigned short* xb = (unsigned short*)((char*)d_ws + WT_BYTES);
        prep<<<dim3(4, 16, 64), 256, 0, stream>>>(Wc, x, Wt, xb);
        concept_256<<<dim3(8, 64), 512, SMEM_DYN, stream>>>(
            xb, Wt, bc, wp, bp, out);
    } else {
        concept_fallback<<<dim3(16, 64), 512, 0, stream>>>(
            x, Wc, bc, wp, bp, out);
    }
}

// Round 4
// 192.618 us; speedup vs baseline: 1.0736x; 1.0285x over previous
//
#include <hip/hip_runtime.h>
#include <hip/hip_bf16.h>

typedef __attribute__((ext_vector_type(8))) short short8v;
typedef __attribute__((ext_vector_type(4))) float floatx4;

#define B_ROWS 2048
#define K_DIM  1024
#define N_CON  64
#define TWO_E  256
#define E_DIM  128
#define BM     128
#define BK     64
#define LDSA_BYTES (BM * BK * 2)              // 16384
#define LDSB_BYTES (TWO_E * BK * 2)           // 32768
#define SMEM_BYTES (LDSA_BYTES + LDSB_BYTES)  // 49152
#define EMB_ELEMS 16777216ULL                 // 2048*64*128
#define WT_BYTES  33554432ULL                 // 64*256*1024*2
#define XB_BYTES  4194304ULL                  // 2048*1024*2

// fp32 -> bf16 bit pattern via proven __float2bfloat16 + memcpy punning.
static __device__ inline unsigned short bf16bits(float f) {
    __hip_bfloat16 h = __float2bfloat16(f);
    unsigned short u;
    __builtin_memcpy(&u, &h, 2);
    return u;
}

// Async 16B global->LDS DMA. LDS dest = wave-uniform base + lane*16 (m104).
static __device__ inline void dma16(const void* g, void* l) {
    __builtin_amdgcn_global_load_lds(
        (const __attribute__((address_space(1))) unsigned int*)g,
        (__attribute__((address_space(3))) unsigned int*)l,
        16, 0, 0);
}

// ---------------------------------------------------------------------------
// Pre-pass (unchanged, verified): W[n][k][o] fp32 -> Wt[n][o][k] bf16;
// x fp32 -> xb bf16. Grid (4,16,64).
// ---------------------------------------------------------------------------
__global__ void __launch_bounds__(256) prep(const float* __restrict__ W,
                                            const float* __restrict__ x,
                                            unsigned short* __restrict__ Wt,
                                            unsigned short* __restrict__ xb) {
    __shared__ unsigned int lds2[64 * 36];   // [o][kpair], padded rows
    const int tid = threadIdx.x;
    const int ot = blockIdx.x, ktile = blockIdx.y, n = blockIdx.z;
    const float* src = W + ((size_t)n * K_DIM + (size_t)ktile * 64) * TWO_E + ot * 64;
    unsigned short* dst = Wt + ((size_t)n * TWO_E + (size_t)ot * 64) * K_DIM + ktile * 64;

    const int kp = tid >> 4;
    const int c  = (tid & 15) * 4;
#pragma unroll
    for (int it = 0; it < 2; ++it) {
        const int k0 = it * 32 + kp * 2;
        floatx4 r0 = *(const floatx4*)&src[(size_t)k0 * TWO_E + c];
        floatx4 r1 = *(const floatx4*)&src[(size_t)(k0 + 1) * TWO_E + c];
#pragma unroll
        for (int j = 0; j < 4; ++j) {
            unsigned int d = (unsigned int)bf16bits(r0[j]) |
                             ((unsigned int)bf16bits(r1[j]) << 16);
            lds2[(c + j) * 36 + it * 16 + kp] = d;
        }
    }
    __syncthreads();
#pragma unroll
    for (int it = 0; it < 2; ++it) {
        int q = it * 256 + tid;
        int o = q >> 3, kc = q & 7;
        short8v v = *(short8v*)&lds2[o * 36 + kc * 4];
        *(short8v*)&dst[(size_t)o * K_DIM + kc * 8] = v;
    }

    const int bid = blockIdx.x + blockIdx.y * 4 + blockIdx.z * 64;
    const size_t base = (size_t)bid * 512 + (size_t)tid * 2;
    unsigned int d = (unsigned int)bf16bits(x[base]) |
                     ((unsigned int)bf16bits(x[base + 1]) << 16);
    ((unsigned int*)xb)[base >> 1] = d;
}

// ---------------------------------------------------------------------------
// Fused GEMM, round-3 structure (resubmitted — round-3 bench never ran):
//   WG = 256 threads (4 waves), tile 128 rows x 256 cols (one concept).
//   Wave-tile 128x64: acc[8][4], A/B fragments each read from LDS ONCE per
//   K-tile (24 ds_read_b128/wave/K-tile = 42.7 FLOP/B vs round-0's 32).
//   Single 48KB LDS buffer, plain syncthreads loop (compiler-scheduled —
//   no phase/setprio scaffolding; rounds 1-2 showed it regresses here).
//   ~210 VGPR -> 2 waves/SIMD -> 2 independent WGs/CU: cross-WG skew
//   provides stage/compute overlap (round-0's proven mechanism).
//   T1 bijective XCD swizzle: XCD k gets concepts [8k, 8k+8) (Wt slice 4MB,
//   L2-resident) — confirmed FETCH 135->49 MB across rounds 1-2.
// ---------------------------------------------------------------------------
__global__ void __launch_bounds__(256, 2)
concept4(const unsigned short* __restrict__ xb,   // bf16 [2048][1024]
         const unsigned short* __restrict__ Wt,   // bf16 [n][o][k]
         const float* __restrict__ bc,
         const float* __restrict__ wp,
         const float* __restrict__ bp,
         float* __restrict__ out) {
    __shared__ __align__(16) char smem[SMEM_BYTES];
    char* ldsA = smem;
    char* ldsB = smem + LDSA_BYTES;

    const int tid  = threadIdx.x;
    const int wave = tid >> 6;        // 0..3 = o group
    const int lane = tid & 63;
    const int lg   = lane >> 4;       // quad 0..3
    const int l15  = lane & 15;
    const int og   = wave;

    // T1 bijective XCD swizzle over 1024 WGs (1024 % 8 == 0).
    const int lin = blockIdx.y * 16 + blockIdx.x;
    const int nid = (lin & 7) * 128 + (lin >> 3);
    const int rb  = nid & 15;         // 0..15 (128 rows each)
    const int n   = nid >> 4;         // 0..63

    int otile[4];
#pragma unroll
    for (int oi = 0; oi < 4; ++oi) otile[oi] = og * 32 + (oi & 1) * 16 + (oi & 2) * 64;

    floatx4 acc[8][4];
#pragma unroll
    for (int mi = 0; mi < 8; ++mi)
#pragma unroll
        for (int oi = 0; oi < 4; ++oi) acc[mi][oi] = (floatx4){0.f, 0.f, 0.f, 0.f};

    const unsigned short* xrow  = xb + (size_t)rb * BM * K_DIM;
    const unsigned short* wbase = Wt + (size_t)n * TWO_E * K_DIM;

    for (int kt = 0; kt < K_DIM; kt += BK) {
        // ---- stage A: 1024 granules (16KB), 4 waves x 4 chunks ----
#pragma unroll
        for (int it = 0; it < 4; ++it) {
            int c = it * 4 + wave;
            int s = c * 64 + lane;
            int r = s >> 3, g = s & 7;
            dma16(xrow + (size_t)r * K_DIM + kt + ((g ^ (r & 7)) * 8),
                  ldsA + c * 1024);
        }
        // ---- stage B: 2048 granules (32KB), 4 waves x 8 chunks ----
#pragma unroll
        for (int it = 0; it < 8; ++it) {
            int c = it * 4 + wave;
            int s = c * 64 + lane;
            int r = s >> 3, g = s & 7;
            dma16(wbase + (size_t)r * K_DIM + kt + ((g ^ (r & 7)) * 8),
                  ldsB + c * 1024);
        }
        __syncthreads();   // compiler drains vmcnt(0) here — validates DMA

        // ---- compute: quadrant ordering, every fragment read once ----
        short8v afA[4][2], afB[4][2], bf[2][2], bf2[2][2];

        // Q1: A rows 0-63 + B cols oi0,1
#pragma unroll
        for (int ks = 0; ks < 2; ++ks) {
            const int sw = ((ks * 4 + lg) ^ (l15 & 7)) * 16;
#pragma unroll
            for (int mi = 0; mi < 4; ++mi)
                afA[mi][ks] = *(const short8v*)(ldsA + (mi * 16 + l15) * 128 + sw);
#pragma unroll
            for (int oi = 0; oi < 2; ++oi)
                bf[oi][ks] = *(const short8v*)(ldsB + (otile[oi] + l15) * 128 + sw);
        }
#pragma unroll
        for (int mi = 0; mi < 4; ++mi)
#pragma unroll
            for (int oi = 0; oi < 2; ++oi)
#pragma unroll
                for (int ks = 0; ks < 2; ++ks)
                    acc[mi][oi] = __builtin_amdgcn_mfma_f32_16x16x32_bf16(
                        afA[mi][ks], bf[oi][ks], acc[mi][oi], 0, 0, 0);

        // Q2: B cols oi2,3 (A rows 0-63 reused from regs)
#pragma unroll
        for (int ks = 0; ks < 2; ++ks) {
            const int sw = ((ks * 4 + lg) ^ (l15 & 7)) * 16;
#pragma unroll
            for (int oi = 0; oi < 2; ++oi)
                bf2[oi][ks] = *(const short8v*)(ldsB + (otile[2 + oi] + l15) * 128 + sw);
        }
#pragma unroll
        for (int mi = 0; mi < 4; ++mi)
#pragma unroll
            for (int oi = 0; oi < 2; ++oi)
#pragma unroll
                for (int ks = 0; ks < 2; ++ks)
                    acc[mi][2 + oi] = __builtin_amdgcn_mfma_f32_16x16x32_bf16(
                        afA[mi][ks], bf2[oi][ks], acc[mi][2 + oi], 0, 0, 0);

        // Q3: A rows 64-127 (B cols oi2,3 reused from regs)
#pragma unroll
        for (int ks = 0; ks < 2; ++ks) {
            const int sw = ((ks * 4 + lg) ^ (l15 & 7)) * 16;
#pragma unroll
            for (int mi = 0; mi < 4; ++mi)
                afB[mi][ks] = *(const short8v*)(ldsA + (64 + mi * 16 + l15) * 128 + sw);
        }
#pragma unroll
        for (int mi = 0; mi < 4; ++mi)
#pragma unroll
            for (int oi = 0; oi < 2; ++oi)
#pragma unroll
                for (int ks = 0; ks < 2; ++ks)
                    acc[4 + mi][2 + oi] = __builtin_amdgcn_mfma_f32_16x16x32_bf16(
                        afB[mi][ks], bf2[oi][ks], acc[4 + mi][2 + oi], 0, 0, 0);

        // Q4: A rows 64-127 x B cols oi0,1 (both reused from regs)
#pragma unroll
        for (int mi = 0; mi < 4; ++mi)
#pragma unroll
            for (int oi = 0; oi < 2; ++oi)
#pragma unroll
                for (int ks = 0; ks < 2; ++ks)
                    acc[4 + mi][oi] = __builtin_amdgcn_mfma_f32_16x16x32_bf16(
                        afB[mi][ks], bf[oi][ks], acc[4 + mi][oi], 0, 0, 0);

        __syncthreads();   // protect buffer before next stage overwrites
    }

    // ---- epilogue (fp32) ----
    float biasf[4], wpf[4];
#pragma unroll
    for (int oi = 0; oi < 4; ++oi) {
        int o = otile[oi] + l15;
        biasf[oi] = bc[n * TWO_E + o];
        wpf[oi]  = wp[o];
    }
#pragma unroll
    for (int mi = 0; mi < 8; ++mi)
#pragma unroll
        for (int oi = 0; oi < 4; ++oi)
#pragma unroll
            for (int j = 0; j < 4; ++j) {
                float v = acc[mi][oi][j] + biasf[oi];
                acc[mi][oi][j] = v >= 0.f ? v : 0.01f * v;   // LeakyReLU
            }

    float* partial = (float*)smem;            // [128][4]
    float* pv      = (float*)(smem + 2048);   // [128]

#pragma unroll
    for (int mi = 0; mi < 8; ++mi)
#pragma unroll
        for (int j = 0; j < 4; ++j) {
            float ps = 0.f;
#pragma unroll
            for (int oi = 0; oi < 4; ++oi) ps += acc[mi][oi][j] * wpf[oi];
            ps += __shfl_xor(ps, 1);
            ps += __shfl_xor(ps, 2);
            ps += __shfl_xor(ps, 4);
            ps += __shfl_xor(ps, 8);
            if (l15 == 0) partial[(mi * 16 + lg * 4 + j) * 4 + og] = ps;
        }
    __syncthreads();

    if (tid < 128) {
        float s = partial[tid * 4] + partial[tid * 4 + 1] + partial[tid * 4 + 2] +
                  partial[tid * 4 + 3] + bp[0];
        float p = 1.f / (1.f + __expf(-s));
        pv[tid] = p;
        size_t bi = (size_t)rb * BM + tid;
        out[EMB_ELEMS + bi * N_CON + n] = p;    // c_pred
    }
    __syncthreads();

#pragma unroll
    for (int mi = 0; mi < 8; ++mi)
#pragma unroll
        for (int oi = 0; oi < 2; ++oi)
#pragma unroll
            for (int j = 0; j < 4; ++j) {
                int row = mi * 16 + lg * 4 + j;
                int e = og * 32 + oi * 16 + l15;
                float p = pv[row];
                float v = acc[mi][oi][j] * p + acc[mi][oi + 2][j] * (1.f - p);
                size_t bi = (size_t)rb * BM + row;
                out[(bi * N_CON + n) * E_DIM + e] = v;
            }
}

// ---------------------------------------------------------------------------
// Fallback (no workspace): round-0 single-buffered fp32-staging kernel.
// ---------------------------------------------------------------------------
__global__ void __launch_bounds__(512, 4)
concept_fallback(const float* __restrict__ x,
                 const float* __restrict__ Wc,
                 const float* __restrict__ bc,
                 const float* __restrict__ wp,
                 const float* __restrict__ bp,
                 float* __restrict__ out) {
    __shared__ __align__(16) char smem[SMEM_BYTES];
    char* ldsA = smem;
    char* ldsB = smem + LDSA_BYTES;

    const int tid  = threadIdx.x;
    const int wave = tid >> 6;
    const int lane = tid & 63;
    const int lg   = lane >> 4;
    const int l15  = lane & 15;
    const int h    = wave >> 2;
    const int og   = wave & 3;
    const int rb = blockIdx.x;
    const int n  = blockIdx.y;

    int otile[4];
#pragma unroll
    for (int oi = 0; oi < 4; ++oi) otile[oi] = og * 32 + (oi & 1) * 16 + (oi & 2) * 64;

    floatx4 acc[4][4];
#pragma unroll
    for (int mi = 0; mi < 4; ++mi)
#pragma unroll
        for (int oi = 0; oi < 4; ++oi) acc[mi][oi] = (floatx4){0.f, 0.f, 0.f, 0.f};

    const float* xg = x + (size_t)rb * BM * K_DIM;
    const float* wg = Wc + (size_t)n * K_DIM * TWO_E;

    for (int kt = 0; kt < K_DIM; kt += BK) {
#pragma unroll
        for (int it = 0; it < 2; ++it) {
            int s = it * 512 + tid;
            int r = s >> 3, g = s & 7;
            const float* p = xg + (size_t)r * K_DIM + kt + ((g ^ (r & 7)) * 8);
            floatx4 v0 = *(const floatx4*)p, v1 = *(const floatx4*)(p + 4);
            short8v b;
            b[0] = (short)bf16bits(v0[0]); b[1] = (short)bf16bits(v0[1]);
            b[2] = (short)bf16bits(v0[2]); b[3] = (short)bf16bits(v0[3]);
            b[4] = (short)bf16bits(v1[0]); b[5] = (short)bf16bits(v1[1]);
            b[6] = (short)bf16bits(v1[2]); b[7] = (short)bf16bits(v1[3]);
            *(short8v*)(ldsA + s * 16) = b;
        }
#pragma unroll
        for (int it = 0; it < 4; ++it) {
            int s = it * 512 + tid;
            int r = s >> 3, g = s & 7;
            int k0 = kt + (g ^ (r & 7)) * 8;
            short8v b;
#pragma unroll
            for (int j = 0; j < 8; ++j)
                b[j] = (short)bf16bits(wg[(size_t)(k0 + j) * TWO_E + r]);
            *(short8v*)(ldsB + s * 16) = b;
        }
        __syncthreads();

#pragma unroll
        for (int ks = 0; ks < 2; ++ks) {
            const int sw = ((ks * 4 + lg) ^ (l15 & 7)) * 16;
            short8v af[4], bfr[4];
#pragma unroll
            for (int mi = 0; mi < 4; ++mi)
                af[mi] = *(const short8v*)(ldsA + (h * 64 + mi * 16 + l15) * 128 + sw);
#pragma unroll
            for (int oi = 0; oi < 4; ++oi)
                bfr[oi] = *(const short8v*)(ldsB + (otile[oi] + l15) * 128 + sw);
#pragma unroll
            for (int mi = 0; mi < 4; ++mi)
#pragma unroll
                for (int oi = 0; oi < 4; ++oi)
                    acc[mi][oi] = __builtin_amdgcn_mfma_f32_16x16x32_bf16(
                        af[mi], bfr[oi], acc[mi][oi], 0, 0, 0);
        }
        __syncthreads();
    }

    float biasf[4], wpf[4];
#pragma unroll
    for (int oi = 0; oi < 4; ++oi) {
        int o = otile[oi] + l15;
        biasf[oi] = bc[n * TWO_E + o];
        wpf[oi]  = wp[o];
    }
#pragma unroll
    for (int mi = 0; mi < 4; ++mi)
#pragma unroll
        for (int oi = 0; oi < 4; ++oi)
#pragma unroll
            for (int j = 0; j < 4; ++j) {
                float v = acc[mi][oi][j] + biasf[oi];
                acc[mi][oi][j] = v >= 0.f ? v : 0.01f * v;
            }

    float* partial = (float*)smem;
    float* pv      = (float*)(smem + 2048);

#pragma unroll
    for (int mi = 0; mi < 4; ++mi)
#pragma unroll
        for (int j = 0; j < 4; ++j) {
            float ps = 0.f;
#pragma unroll
            for (int oi = 0; oi < 4; ++oi) ps += acc[mi][oi][j] * wpf[oi];
            ps += __shfl_xor(ps, 1);
            ps += __shfl_xor(ps, 2);
            ps += __shfl_xor(ps, 4);
            ps += __shfl_xor(ps, 8);
            if (l15 == 0) partial[(h * 64 + mi * 16 + lg * 4 + j) * 4 + og] = ps;
        }
    __syncthreads();

    if (tid < 128) {
        float s = partial[tid * 4] + partial[tid * 4 + 1] + partial[tid * 4 + 2] +
                  partial[tid * 4 + 3] + bp[0];
        float p = 1.f / (1.f + __expf(-s));
        pv[tid] = p;
        size_t bi = (size_t)rb * BM + tid;
        out[EMB_ELEMS + bi * N_CON + n] = p;
    }
    __syncthreads();

#pragma unroll
    for (int mi = 0; mi < 4; ++mi)
#pragma unroll
        for (int oi = 0; oi < 2; ++oi)
#pragma unroll
            for (int j = 0; j < 4; ++j) {
                int row = h * 64 + mi * 16 + lg * 4 + j;
                int e = og * 32 + oi * 16 + l15;
                float p = pv[row];
                float v = acc[mi][oi][j] * p + acc[mi][oi + 2][j] * (1.f - p);
                size_t bi = (size_t)rb * BM + row;
                out[(bi * N_CON + n) * E_DIM + e] = v;
            }
}

extern "C" void kernel_launch(void* const* d_in, const int* in_sizes, int n_in,
                              void* d_out, int out_size, void* d_ws, size_t ws_size,
                              hipStream_t stream) {
    const float* x  = (const float*)d_in[0];
    const float* Wc = (const float*)d_in[1];
    const float* bc = (const float*)d_in[2];
    const float* wp = (const float*)d_in[3];
    const float* bp = (const float*)d_in[4];
    float* out = (float*)d_out;

    if (ws_size >= WT_BYTES + XB_BYTES) {
        unsigned short* Wt = (unsigned short*)d_ws;
        unsigned short* xb = (unsigned short*)((char*)d_ws + WT_BYTES);
        prep<<<dim3(4, 16, 64), 256, 0, stream>>>(Wc, x, Wt, xb);
        concept4<<<dim3(16, 64), 256, 0, stream>>>(xb, Wt, bc, wp, bp, out);
    } else {
        concept_fallback<<<dim3(16, 64), 512, 0, stream>>>(
            x, Wc, bc, wp, bp, out);
    }
}